// Round 14
// baseline (275.133 us; speedup 1.0000x reference)
//
#include <hip/hip_runtime.h>
#include <cstdint>

// NewsEncoder: B=8192, L=64, D=256, H=8, DH=32, VOCAB=50000.
// R14: (1) main staging via global_load_lds width=16 (linear LDS dest,
// source-side XOR swizzle chunk^=(row&7), same XOR on phase-1/4 reads;
// LDS 40,960->39,680, no VGPR round-trip). (2) pgemm: grid (256,4) 32-row
// tiles -> 1024 blocks (R12's 512 = 2/CU was latency-starved).
// Workspace: mbf | xbf | tkn | cbf | ebf | ptb  => ~62.4 MB

using f32x4  = __attribute__((ext_vector_type(4))) float;
using bf16x8 = __attribute__((ext_vector_type(8))) short;

__device__ __forceinline__ unsigned int pack2bf(float a, float b) {
  unsigned int ua = __builtin_bit_cast(unsigned int, a);
  unsigned int ub = __builtin_bit_cast(unsigned int, b);
  ua = (ua + 0x7fffu + ((ua >> 16) & 1u)) >> 16;   // RTNE to bf16
  ub = (ub + 0x7fffu + ((ub >> 16) & 1u)) >> 16;
  return ua | (ub << 16);
}
__device__ __forceinline__ unsigned short bf1(float a) {
  unsigned int ua = __builtin_bit_cast(unsigned int, a);
  ua = (ua + 0x7fffu + ((ua >> 16) & 1u)) >> 16;
  return (unsigned short)ua;
}
__device__ __forceinline__ float ubf(unsigned int u) {
  return __builtin_bit_cast(float, u << 16);
}
__device__ __forceinline__ void gload_lds16(const void* g, void* l) {
  __builtin_amdgcn_global_load_lds(
      (const __attribute__((address_space(1))) void*)g,
      (__attribute__((address_space(3))) void*)l, 16, 0, 0);
}

// ---- prep: WOd[d] = WO[d,:]@dw;  m[h][d] = sum_j WV[d][h*32+j]*WOd[h*32+j] (bf16 out)
__global__ __launch_bounds__(256) void prep_kernel(const float* __restrict__ WV,
                                                   const float* __restrict__ WO,
                                                   const float* __restrict__ dw,
                                                   unsigned short* __restrict__ mbf) {
  __shared__ float wod[256];
  const int t = threadIdx.x;
  float acc = 0.f;
  for (int e = 0; e < 256; e += 4) {
    const float4 w4 = *(const float4*)(WO + (size_t)t * 256 + e);
    const float4 d4 = *(const float4*)(dw + e);
    acc += w4.x * d4.x + w4.y * d4.y + w4.z * d4.z + w4.w * d4.w;
  }
  wod[t] = acc;
  __syncthreads();
  for (int h = 0; h < 8; ++h) {
    float a = 0.f;
    for (int j = 0; j < 32; j += 4) {
      const float4 w4 = *(const float4*)(WV + (size_t)t * 256 + h * 32 + j);
      a += w4.x * wod[h*32+j] + w4.y * wod[h*32+j+1] + w4.z * wod[h*32+j+2] + w4.w * wod[h*32+j+3];
    }
    const float o = __shfl_xor(a, 1);
    if (!(t & 1)) ((unsigned int*)mbf)[h * 128 + (t >> 1)] = pack2bf(a, o);
  }
}

// ---- prep_T: Tkn[n=h*256+e][d] = sum_j WQ[d][hj]*WK[e][hj] + WK[d][hj]*WQ[e][hj] (bf16)
__global__ __launch_bounds__(256) void prep_T(const float* __restrict__ WQ,
                                              const float* __restrict__ WK,
                                              unsigned short* __restrict__ tkn) {
  __shared__ float ek[8][32], eq[8][32];
  const int t = threadIdx.x;
  const int n0 = blockIdx.x * 8;          // 8 n-rows per block, same head
  const int h  = n0 >> 8;
  {
    const int ei = t >> 5, j = t & 31;
    const int e = (n0 & 255) + ei;
    ek[ei][j] = WK[(size_t)e * 256 + h * 32 + j];
    eq[ei][j] = WQ[(size_t)e * 256 + h * 32 + j];
  }
  __syncthreads();
  float wqd[32], wkd[32];
#pragma unroll
  for (int j = 0; j < 32; j += 4) {
    *(float4*)(wqd + j) = *(const float4*)(WQ + (size_t)t * 256 + h * 32 + j);
    *(float4*)(wkd + j) = *(const float4*)(WK + (size_t)t * 256 + h * 32 + j);
  }
#pragma unroll
  for (int ei = 0; ei < 8; ++ei) {
    float a = 0.f;
#pragma unroll
    for (int j = 0; j < 32; ++j) a += wqd[j] * ek[ei][j] + wkd[j] * eq[ei][j];
    const float o = __shfl_xor(a, 1);
    if (!(t & 1)) ((unsigned int*)tkn)[(size_t)(n0 + ei) * 128 + (t >> 1)] = pack2bf(a, o);
  }
}

// ---- prep_P: Pt[n][h*256+d] = sum_j WV[d][h*32+j] * WO[h*32+j][n]  (bf16, transposed)
__global__ __launch_bounds__(256) void prep_P(const float* __restrict__ WV,
                                              const float* __restrict__ WO,
                                              unsigned short* __restrict__ ptb) {
  __shared__ float wvs[32][32];    // WV[d0+dd][h32+j]
  __shared__ float wos[32][256];   // WO[h32+j][n]
  const int t = threadIdx.x;
  const int h = blockIdx.x, d0 = blockIdx.y * 32;
  {
    const int dd = t >> 3, jq = (t & 7) * 4;
    *(float4*)(&wvs[dd][jq]) = *(const float4*)(WV + (size_t)(d0 + dd) * 256 + h * 32 + jq);
    const int c4 = (t & 63) * 4;
#pragma unroll
    for (int jj = 0; jj < 8; ++jj) {
      const int j = (t >> 6) * 8 + jj;
      *(float4*)(&wos[j][c4]) = *(const float4*)(WO + (size_t)(h * 32 + j) * 256 + c4);
    }
  }
  __syncthreads();
  const int n = t;
#pragma unroll 4
  for (int dd = 0; dd < 32; ++dd) {
    float a = 0.f;
#pragma unroll
    for (int j = 0; j < 32; ++j) a += wvs[dd][j] * wos[j][n];
    ptb[(size_t)n * 2048 + h * 256 + d0 + dd] = bf1(a);
  }
}

// ---- K0: convert emb (f32) -> ebf (bf16)
__global__ __launch_bounds__(256) void ebf_kernel(const float4* __restrict__ emb4,
                                                  uint2* __restrict__ out2, int n) {
  for (int i = blockIdx.x * 256 + threadIdx.x; i < n; i += gridDim.x * 256) {
    const float4 v = emb4[i];
    uint2 pk;
    pk.x = pack2bf(v.x, v.y);
    pk.y = pack2bf(v.z, v.w);
    out2[i] = pk;
  }
}

// ---- K1: xbar[b][d] = mean_l ebf[tok[b][l]][d]  (bf16 in/out, f32 accum)
__global__ __launch_bounds__(256) void xbar_kernel(const int* __restrict__ tokens,
                                                   const unsigned short* __restrict__ ebf,
                                                   unsigned short* __restrict__ xbf) {
  __shared__ int tok[64];
  __shared__ float part[4][64][4];          // 4 KB
  const int b = blockIdx.x, t = threadIdx.x;
  if (t < 64) tok[t] = tokens[b * 64 + t];
  __syncthreads();
  const int cp = t & 63, rg = t >> 6;       // col-quad, row-group
  const uint2* e2 = (const uint2*)ebf;
  float s0 = 0.f, s1 = 0.f, s2 = 0.f, s3 = 0.f;
#pragma unroll
  for (int ri = 0; ri < 16; ++ri) {
    const uint2 u = e2[(size_t)tok[rg * 16 + ri] * 64 + cp];
    s0 += ubf(u.x & 0xffffu); s1 += ubf(u.x >> 16);
    s2 += ubf(u.y & 0xffffu); s3 += ubf(u.y >> 16);
  }
  *(float4*)part[rg][cp] = make_float4(s0, s1, s2, s3);
  __syncthreads();
  if (t < 64) {
    const float4 p0 = *(const float4*)part[0][t];
    const float4 p1 = *(const float4*)part[1][t];
    const float4 p2 = *(const float4*)part[2][t];
    const float4 p3 = *(const float4*)part[3][t];
    const float a0 = (p0.x + p1.x + p2.x + p3.x) * (1.f / 64.f);
    const float a1 = (p0.y + p1.y + p2.y + p3.y) * (1.f / 64.f);
    const float a2 = (p0.z + p1.z + p2.z + p3.z) * (1.f / 64.f);
    const float a3 = (p0.w + p1.w + p2.w + p3.w) * (1.f / 64.f);
    uint2 pk;
    pk.x = pack2bf(a0, a1);
    pk.y = pack2bf(a2, a3);
    *(uint2*)((unsigned int*)xbf + (size_t)b * 128 + 2 * t) = pk;
  }
}

// ---- K2: cbf[b][n] = sum_d xbf[b][d] * tkn[n][d]  (bf16 MFMA GEMM)
__global__ __launch_bounds__(256) void cgemm(const unsigned short* __restrict__ xbf,
                                             const unsigned short* __restrict__ tkn,
                                             unsigned short* __restrict__ cbf) {
  __shared__ unsigned short As[64 * 264];   // 33,792 B
  const int t = threadIdx.x;
  const int m0 = blockIdx.x * 64, n0 = blockIdx.y * 64;
#pragma unroll
  for (int it = 0; it < 8; ++it) {
    const int idx = it * 256 + t;
    const int row = idx >> 5, c = idx & 31;
    const uint4 v = *(const uint4*)(xbf + (size_t)(m0 + row) * 256 + c * 8);
    *(uint4*)(As + row * 264 + c * 8) = v;
  }
  __syncthreads();
  const int wv = t >> 6, l = t & 63;
  const int g = l >> 4, r = l & 15;
#pragma unroll
  for (int nt = 0; nt < 4; ++nt) {
    const int n = n0 + nt * 16 + r;
    f32x4 acc = {0.f, 0.f, 0.f, 0.f};
#pragma unroll
    for (int kk = 0; kk < 8; ++kk) {
      const bf16x8 a  = *(const bf16x8*)(As + (16 * wv + r) * 264 + kk * 32 + g * 8);
      const bf16x8 bb = *(const bf16x8*)(tkn + (size_t)n * 256 + kk * 32 + g * 8);
      acc = __builtin_amdgcn_mfma_f32_16x16x32_bf16(a, bb, acc, 0, 0, 0);
    }
#pragma unroll
    for (int i = 0; i < 4; ++i)
      cbf[(size_t)(m0 + 16 * wv + g * 4 + i) * 2048 + n] = bf1(acc[i]);
  }
}

// ---- K3: main v5 — staging via global_load_lds (linear dest, source-side
//          XOR swizzle chunk^=(row&7)); phases as v4 with swizzled reads.
__global__ __launch_bounds__(256) void main_kernel(const int* __restrict__ tokens,
                                                   const unsigned short* __restrict__ ebf,
                                                   const unsigned short* __restrict__ mbf,
                                                   const float* __restrict__ dense_b,
                                                   unsigned short* __restrict__ cbf) {
  __shared__ unsigned short xl[64 * 256];   // 32,768 B: x bf16, LINEAR, swizzled
  __shared__ float wslds[64 * 17];          // 4,352 B: cols 0-7 w->p, 8-15 s
  __shared__ unsigned short cfT[16 * 80];   // 2,560 B: coef^T bf16 [h][l]
  const int t = threadIdx.x;
  const int b = blockIdx.x;
  const int wv = t >> 6, l = t & 63;
  const int g = l >> 4, r = l & 15;
  // zero cfT rows 8..15 (M-padding read by MFMA; keep deterministic)
  {
    unsigned int* cz = (unsigned int*)(cfT + 8 * 80);
    for (int z = t; z < 320; z += 256) cz[z] = 0u;
  }
  // Stage x via global_load_lds: wave writes 1024B linear (2 rows x 32 chunks);
  // source chunk pre-swizzled: LDS[R][j] holds global chunk j^(R&7).
  {
    const int ln = t & 63;
#pragma unroll
    for (int it = 0; it < 8; ++it) {
      const int R0 = it * 8 + wv * 2;          // wave-uniform base row
      const int R  = R0 + (ln >> 5);
      const int j  = ln & 31;
      const int tk = tokens[b * 64 + R];
      const unsigned short* src = ebf + (size_t)tk * 256 + ((j ^ (R & 7)) << 3);
      gload_lds16(src, (void*)(xl + R0 * 256));
    }
  }
  __syncthreads();                          // barrier 1: x staged
  // Phase 1: [W|S] = X[64,256] @ [c|m]^T; A from LDS (swizzled), B from global
  {
    const unsigned short* arow = xl + (16 * wv + r) * 256;
    const int sw = r & 7;
    const unsigned short* brow = (r < 8) ? (cbf + (size_t)b * 2048 + r * 256)
                                         : (mbf + (size_t)(r - 8) * 256);
    f32x4 acc = {0.f, 0.f, 0.f, 0.f};
#pragma unroll
    for (int kk = 0; kk < 8; ++kk) {
      const bf16x8 a  = *(const bf16x8*)(arow + (((kk * 4 + g) ^ sw) << 3));
      const bf16x8 bb = *(const bf16x8*)(brow + kk * 32 + g * 8);
      acc = __builtin_amdgcn_mfma_f32_16x16x32_bf16(a, bb, acc, 0, 0, 0);
    }
#pragma unroll
    for (int i = 0; i < 4; ++i)
      wslds[(16 * wv + g * 4 + i) * 17 + r] = acc[i];
  }
  __syncthreads();                          // barrier 2: logits complete
  // Phase 2: per-head softmax over seq (wave w handles heads 2w, 2w+1)
  {
#pragma unroll
    for (int hh = 0; hh < 2; ++hh) {
      const int h = 2 * wv + hh;
      const float v = wslds[l * 17 + h];
      float mx = v;
#pragma unroll
      for (int sft = 32; sft; sft >>= 1) mx = fmaxf(mx, __shfl_xor(mx, sft));
      const float e = expf(v - mx);
      float sm = e;
#pragma unroll
      for (int sft = 32; sft; sft >>= 1) sm += __shfl_xor(sm, sft);
      wslds[l * 17 + h] = e / sm;
    }
  }
  __syncthreads();                          // barrier 3: p complete
  // Phase 3 (every wave, redundant): scores softmax -> coef -> cfT (bf16)
  {
    float p[8], sv[8];
#pragma unroll
    for (int h = 0; h < 8; ++h) { p[h] = wslds[l*17 + h]; sv[h] = wslds[l*17 + 8 + h]; }
    float sc = dense_b[0];
#pragma unroll
    for (int h = 0; h < 8; ++h) sc += p[h] * sv[h];
    float mx = sc;
#pragma unroll
    for (int sft = 32; sft; sft >>= 1) mx = fmaxf(mx, __shfl_xor(mx, sft));
    const float e = expf(sc - mx);
    float sm = e;
#pragma unroll
    for (int sft = 32; sft; sft >>= 1) sm += __shfl_xor(sm, sft);
    const float attn = e / sm;
    float cc0, cc1;
    if      (wv == 0) { cc0 = attn * p[0]; cc1 = attn * p[1]; }
    else if (wv == 1) { cc0 = attn * p[2]; cc1 = attn * p[3]; }
    else if (wv == 2) { cc0 = attn * p[4]; cc1 = attn * p[5]; }
    else              { cc0 = attn * p[6]; cc1 = attn * p[7]; }
    cfT[(2 * wv) * 80 + l]     = bf1(cc0);   // coefT[h][l]
    cfT[(2 * wv + 1) * 80 + l] = bf1(cc1);
  }
  __syncthreads();                          // barrier 4: cfT ready
  // Phase 4: Y = coefT @ X via MFMA (swizzled column reads of xl).
  {
    const bf16x8 a0 = *(const bf16x8*)(cfT + r * 80 + g * 8);        // k = 0..31
    const bf16x8 a1 = *(const bf16x8*)(cfT + r * 80 + 32 + g * 8);   // k = 32..63
    const short* xs = (const short*)xl;
#pragma unroll
    for (int nt = 0; nt < 4; ++nt) {
      const int d = wv * 64 + nt * 16 + r;
      short bv0[8], bv1[8];
#pragma unroll
      for (int j = 0; j < 8; ++j) {
        const int off = ((((d >> 3) ^ j) << 3) | (d & 7));
        bv0[j] = xs[(g * 8 + j) * 256 + off];        // X[l=g*8+j][d]
        bv1[j] = xs[(32 + g * 8 + j) * 256 + off];   // X[l=32+g*8+j][d]
      }
      f32x4 acc = {0.f, 0.f, 0.f, 0.f};
      acc = __builtin_amdgcn_mfma_f32_16x16x32_bf16(a0, *(const bf16x8*)bv0, acc, 0, 0, 0);
      acc = __builtin_amdgcn_mfma_f32_16x16x32_bf16(a1, *(const bf16x8*)bv1, acc, 0, 0, 0);
      if (g < 2) {
#pragma unroll
        for (int i = 0; i < 4; ++i) {
          const int h = g * 4 + i;                  // rows 0..7 valid
          cbf[(size_t)b * 2048 + h * 256 + d] = bf1(acc[i]);
        }
      }
    }
  }
}

// ---- K4: out[8192,256] = cbf[8192,2048] @ P  (MFMA; 32-row tiles, 1024 blocks)
__global__ __launch_bounds__(256) void pgemm(const unsigned short* __restrict__ cbf,
                                             const unsigned short* __restrict__ ptb,
                                             float* __restrict__ out) {
  __shared__ unsigned short As[32 * 264];   // 16,896 B: 32 rows x 256 bf16 K-chunk
  const int t = threadIdx.x;
  const int m0 = blockIdx.x * 32, n0 = blockIdx.y * 64;
  const int wv = t >> 6, l = t & 63;
  const int g = l >> 4, r = l & 15;
  const int msub = wv & 1, nhalf = wv >> 1;
  f32x4 acc[2] = {};
  for (int kc = 0; kc < 8; ++kc) {          // K chunks of 256
    __syncthreads();                        // As reuse guard (no-op at kc=0)
#pragma unroll
    for (int it = 0; it < 4; ++it) {
      const int idx = it * 256 + t;          // 0..1023
      const int row = idx >> 5, c = idx & 31;
      const uint4 v = *(const uint4*)(cbf + (size_t)(m0 + row) * 2048 + kc * 256 + c * 8);
      *(uint4*)(As + row * 264 + c * 8) = v;
    }
    __syncthreads();
#pragma unroll
    for (int kk = 0; kk < 8; ++kk) {
      const bf16x8 a = *(const bf16x8*)(As + (16 * msub + r) * 264 + kk * 32 + g * 8);
#pragma unroll
      for (int nt = 0; nt < 2; ++nt) {
        const int n = n0 + (nhalf * 2 + nt) * 16 + r;
        const bf16x8 bb = *(const bf16x8*)(ptb + (size_t)n * 2048 + kc * 256 + kk * 32 + g * 8);
        acc[nt] = __builtin_amdgcn_mfma_f32_16x16x32_bf16(a, bb, acc[nt], 0, 0, 0);
      }
    }
  }
#pragma unroll
  for (int nt = 0; nt < 2; ++nt) {
    const int n = n0 + (nhalf * 2 + nt) * 16 + r;
#pragma unroll
    for (int i = 0; i < 4; ++i)
      out[(size_t)(m0 + 16 * msub + g * 4 + i) * 256 + n] = acc[nt][i];
  }
}

extern "C" void kernel_launch(void* const* d_in, const int* in_sizes, int n_in,
                              void* d_out, int out_size, void* d_ws, size_t ws_size,
                              hipStream_t stream) {
  const int*   tokens = (const int*)d_in[0];
  const float* emb    = (const float*)d_in[1];
  const float* WQ     = (const float*)d_in[2];
  const float* WK     = (const float*)d_in[3];
  const float* WV     = (const float*)d_in[4];
  const float* WO     = (const float*)d_in[5];
  const float* dw     = (const float*)d_in[6];
  const float* db     = (const float*)d_in[7];
  float* out = (float*)d_out;

  // ushort-unit layout
  unsigned short* base = (unsigned short*)d_ws;
  unsigned short* mbf  = base;                           // 2048
  unsigned short* xbf  = base + 2048;                    // 8192*256   (4 MB)
  unsigned short* tkn  = xbf + (size_t)8192 * 256;       // 2048*256   (1 MB)
  unsigned short* cbf  = tkn + (size_t)2048 * 256;       // 8192*2048  (32 MB)
  unsigned short* ebf  = cbf + (size_t)8192 * 2048;      // 50000*256  (25.6 MB)
  unsigned short* ptb  = ebf + (size_t)50000 * 256;      // 256*2048   (1 MB)

  const size_t need_bytes = (size_t)(2048 + 8192*256 + 2048*256 + 8192*2048
                                     + 50000*256 + 256*2048) * 2;
  if (ws_size < need_bytes) return;  // deterministic no-op guard

  prep_kernel<<<dim3(1), dim3(256), 0, stream>>>(WV, WO, dw, mbf);
  prep_T<<<dim3(256), dim3(256), 0, stream>>>(WQ, WK, tkn);
  prep_P<<<dim3(8, 8), dim3(256), 0, stream>>>(WV, WO, ptb);
  // emb f32 -> ebf bf16 (50000*256)
  ebf_kernel<<<dim3(2048), dim3(256), 0, stream>>>((const float4*)emb, (uint2*)ebf,
                                                   50000 * 64);
  xbar_kernel<<<dim3(8192), dim3(256), 0, stream>>>(tokens, ebf, xbf);
  // c[b][n] for all b,n in one MFMA GEMM
  cgemm<<<dim3(128, 32), dim3(256), 0, stream>>>(xbf, tkn, cbf);
  // main per-sample: logits, softmaxes, y via MFMA (overwrites c, bf16)
  main_kernel<<<dim3(8192), dim3(256), 0, stream>>>(tokens, ebf, mbf, db, cbf);
  // out = Y @ P in one MFMA GEMM (1024 blocks, 32x64 tiles)
  pgemm<<<dim3(256, 4), dim3(256), 0, stream>>>(cbf, ptb, out);
}

// Round 15
// 260.710 us; speedup vs baseline: 1.0553x; 1.0553x over previous
//
#include <hip/hip_runtime.h>
#include <cstdint>

// NewsEncoder: B=8192, L=64, D=256, H=8, DH=32, VOCAB=50000.
// R15: (1) xbar v2 — uint4 gathers (16B/lane, 8/thread) + LDS cross-reduce
// (xbar moves the same 268MB gather as main with half-width loads; biggest
// invisible chunk). (2) main phase-4 nt-skew (nt=(ntt+r)&3): 8-way -> 4-way
// LDS conflicts, free (B-columns are per-lane independent). (3) preps fused
// into one 321-block launch. R14 lesson: staging/phase-1 were NOT the
// bottleneck (counters unmoved) — conflicts live in phase 4.
// Workspace: mbf | xbf | tkn | cbf | ebf | ptb  => ~62.4 MB

using f32x4  = __attribute__((ext_vector_type(4))) float;
using bf16x8 = __attribute__((ext_vector_type(8))) short;

__device__ __forceinline__ unsigned int pack2bf(float a, float b) {
  unsigned int ua = __builtin_bit_cast(unsigned int, a);
  unsigned int ub = __builtin_bit_cast(unsigned int, b);
  ua = (ua + 0x7fffu + ((ua >> 16) & 1u)) >> 16;   // RTNE to bf16
  ub = (ub + 0x7fffu + ((ub >> 16) & 1u)) >> 16;
  return ua | (ub << 16);
}
__device__ __forceinline__ unsigned short bf1(float a) {
  unsigned int ua = __builtin_bit_cast(unsigned int, a);
  ua = (ua + 0x7fffu + ((ua >> 16) & 1u)) >> 16;
  return (unsigned short)ua;
}
__device__ __forceinline__ float ubf(unsigned int u) {
  return __builtin_bit_cast(float, u << 16);
}
__device__ __forceinline__ void gload_lds16(const void* g, void* l) {
  __builtin_amdgcn_global_load_lds(
      (const __attribute__((address_space(1))) void*)g,
      (__attribute__((address_space(3))) void*)l, 16, 0, 0);
}

// ---- prep_all: block 0 = mbf; blocks 1..256 = tkn; blocks 257..320 = ptb
__global__ __launch_bounds__(256) void prep_all(const float* __restrict__ WQ,
                                                const float* __restrict__ WK,
                                                const float* __restrict__ WV,
                                                const float* __restrict__ WO,
                                                const float* __restrict__ dw,
                                                unsigned short* __restrict__ mbf,
                                                unsigned short* __restrict__ tkn,
                                                unsigned short* __restrict__ ptb) {
  const int t = threadIdx.x;
  const int bid = blockIdx.x;
  if (bid == 0) {
    // mbf: WOd[d] = WO[d,:]@dw; m[h][d] = sum_j WV[d][h32+j]*WOd[h32+j]
    __shared__ float wod[256];
    float acc = 0.f;
    for (int e = 0; e < 256; e += 4) {
      const float4 w4 = *(const float4*)(WO + (size_t)t * 256 + e);
      const float4 d4 = *(const float4*)(dw + e);
      acc += w4.x * d4.x + w4.y * d4.y + w4.z * d4.z + w4.w * d4.w;
    }
    wod[t] = acc;
    __syncthreads();
    for (int h = 0; h < 8; ++h) {
      float a = 0.f;
      for (int j = 0; j < 32; j += 4) {
        const float4 w4 = *(const float4*)(WV + (size_t)t * 256 + h * 32 + j);
        a += w4.x * wod[h*32+j] + w4.y * wod[h*32+j+1] + w4.z * wod[h*32+j+2] + w4.w * wod[h*32+j+3];
      }
      const float o = __shfl_xor(a, 1);
      if (!(t & 1)) ((unsigned int*)mbf)[h * 128 + (t >> 1)] = pack2bf(a, o);
    }
  } else if (bid <= 256) {
    // tkn[n=h*256+e][d] = sum_j WQ[d][hj]*WK[e][hj] + WK[d][hj]*WQ[e][hj]
    __shared__ float ek[8][32], eq[8][32];
    const int n0 = (bid - 1) * 8;
    const int h  = n0 >> 8;
    {
      const int ei = t >> 5, j = t & 31;
      const int e = (n0 & 255) + ei;
      ek[ei][j] = WK[(size_t)e * 256 + h * 32 + j];
      eq[ei][j] = WQ[(size_t)e * 256 + h * 32 + j];
    }
    __syncthreads();
    float wqd[32], wkd[32];
#pragma unroll
    for (int j = 0; j < 32; j += 4) {
      *(float4*)(wqd + j) = *(const float4*)(WQ + (size_t)t * 256 + h * 32 + j);
      *(float4*)(wkd + j) = *(const float4*)(WK + (size_t)t * 256 + h * 32 + j);
    }
#pragma unroll
    for (int ei = 0; ei < 8; ++ei) {
      float a = 0.f;
#pragma unroll
      for (int j = 0; j < 32; ++j) a += wqd[j] * ek[ei][j] + wkd[j] * eq[ei][j];
      const float o = __shfl_xor(a, 1);
      if (!(t & 1)) ((unsigned int*)tkn)[(size_t)(n0 + ei) * 128 + (t >> 1)] = pack2bf(a, o);
    }
  } else {
    // ptb[n][h*256+d] = sum_j WV[d][h32+j] * WO[h32+j][n]  (transposed P, bf16)
    __shared__ float wvs[32][32];
    __shared__ float wos[32][256];
    const int pb = bid - 257;
    const int h = pb >> 3, d0 = (pb & 7) * 32;
    {
      const int dd = t >> 3, jq = (t & 7) * 4;
      *(float4*)(&wvs[dd][jq]) = *(const float4*)(WV + (size_t)(d0 + dd) * 256 + h * 32 + jq);
      const int c4 = (t & 63) * 4;
#pragma unroll
      for (int jj = 0; jj < 8; ++jj) {
        const int j = (t >> 6) * 8 + jj;
        *(float4*)(&wos[j][c4]) = *(const float4*)(WO + (size_t)(h * 32 + j) * 256 + c4);
      }
    }
    __syncthreads();
    const int n = t;
#pragma unroll 4
    for (int dd = 0; dd < 32; ++dd) {
      float a = 0.f;
#pragma unroll
      for (int j = 0; j < 32; ++j) a += wvs[dd][j] * wos[j][n];
      ptb[(size_t)n * 2048 + h * 256 + d0 + dd] = bf1(a);
    }
  }
}

// ---- K0: convert emb (f32) -> ebf (bf16)
__global__ __launch_bounds__(256) void ebf_kernel(const float4* __restrict__ emb4,
                                                  uint2* __restrict__ out2, int n) {
  for (int i = blockIdx.x * 256 + threadIdx.x; i < n; i += gridDim.x * 256) {
    const float4 v = emb4[i];
    uint2 pk;
    pk.x = pack2bf(v.x, v.y);
    pk.y = pack2bf(v.z, v.w);
    out2[i] = pk;
  }
}

// ---- K1: xbar v2 — uint4 gather (8 rows/thread), LDS cross-reduce
__global__ __launch_bounds__(256) void xbar_kernel(const int* __restrict__ tokens,
                                                   const unsigned short* __restrict__ ebf,
                                                   unsigned short* __restrict__ xbf) {
  __shared__ int tok[64];
  __shared__ float part[8][256];            // 8 KB
  const int b = blockIdx.x, t = threadIdx.x;
  if (t < 64) tok[t] = tokens[b * 64 + t];
  __syncthreads();
  const int rg = t >> 5;                    // row-group (8 rows)
  const int c16 = t & 31;                   // 16B chunk (8 bf16)
  const uint4* e4 = (const uint4*)ebf;      // 32 chunks per row
  float s[8] = {};
#pragma unroll
  for (int ri = 0; ri < 8; ++ri) {
    const uint4 u = e4[(size_t)tok[rg * 8 + ri] * 32 + c16];
    s[0] += ubf(u.x & 0xffffu); s[1] += ubf(u.x >> 16);
    s[2] += ubf(u.y & 0xffffu); s[3] += ubf(u.y >> 16);
    s[4] += ubf(u.z & 0xffffu); s[5] += ubf(u.z >> 16);
    s[6] += ubf(u.w & 0xffffu); s[7] += ubf(u.w >> 16);
  }
#pragma unroll
  for (int j = 0; j < 8; ++j) part[rg][c16 * 8 + j] = s[j];
  __syncthreads();
  float a = 0.f;
#pragma unroll
  for (int rg2 = 0; rg2 < 8; ++rg2) a += part[rg2][t];
  a *= (1.f / 64.f);
  const float o = __shfl_xor(a, 1);
  if (!(t & 1)) ((unsigned int*)xbf)[(size_t)b * 128 + (t >> 1)] = pack2bf(a, o);
}

// ---- K2: cbf[b][n] = sum_d xbf[b][d] * tkn[n][d]  (bf16 MFMA GEMM)
__global__ __launch_bounds__(256) void cgemm(const unsigned short* __restrict__ xbf,
                                             const unsigned short* __restrict__ tkn,
                                             unsigned short* __restrict__ cbf) {
  __shared__ unsigned short As[64 * 264];   // 33,792 B
  const int t = threadIdx.x;
  const int m0 = blockIdx.x * 64, n0 = blockIdx.y * 64;
#pragma unroll
  for (int it = 0; it < 8; ++it) {
    const int idx = it * 256 + t;
    const int row = idx >> 5, c = idx & 31;
    const uint4 v = *(const uint4*)(xbf + (size_t)(m0 + row) * 256 + c * 8);
    *(uint4*)(As + row * 264 + c * 8) = v;
  }
  __syncthreads();
  const int wv = t >> 6, l = t & 63;
  const int g = l >> 4, r = l & 15;
#pragma unroll
  for (int nt = 0; nt < 4; ++nt) {
    const int n = n0 + nt * 16 + r;
    f32x4 acc = {0.f, 0.f, 0.f, 0.f};
#pragma unroll
    for (int kk = 0; kk < 8; ++kk) {
      const bf16x8 a  = *(const bf16x8*)(As + (16 * wv + r) * 264 + kk * 32 + g * 8);
      const bf16x8 bb = *(const bf16x8*)(tkn + (size_t)n * 256 + kk * 32 + g * 8);
      acc = __builtin_amdgcn_mfma_f32_16x16x32_bf16(a, bb, acc, 0, 0, 0);
    }
#pragma unroll
    for (int i = 0; i < 4; ++i)
      cbf[(size_t)(m0 + 16 * wv + g * 4 + i) * 2048 + n] = bf1(acc[i]);
  }
}

// ---- K3: main v6 — as v5 but phase-4 nt-skew (nt=(ntt+r)&3): 4-way conflicts
__global__ __launch_bounds__(256) void main_kernel(const int* __restrict__ tokens,
                                                   const unsigned short* __restrict__ ebf,
                                                   const unsigned short* __restrict__ mbf,
                                                   const float* __restrict__ dense_b,
                                                   unsigned short* __restrict__ cbf) {
  __shared__ unsigned short xl[64 * 256];   // 32,768 B: x bf16, LINEAR, swizzled
  __shared__ float wslds[64 * 17];          // 4,352 B
  __shared__ unsigned short cfT[16 * 80];   // 2,560 B
  const int t = threadIdx.x;
  const int b = blockIdx.x;
  const int wv = t >> 6, l = t & 63;
  const int g = l >> 4, r = l & 15;
  {
    unsigned int* cz = (unsigned int*)(cfT + 8 * 80);
    for (int z = t; z < 320; z += 256) cz[z] = 0u;
  }
  // Stage x via global_load_lds: source chunk pre-swizzled j^(R&7)
  {
    const int ln = t & 63;
#pragma unroll
    for (int it = 0; it < 8; ++it) {
      const int R0 = it * 8 + wv * 2;
      const int R  = R0 + (ln >> 5);
      const int j  = ln & 31;
      const int tk = tokens[b * 64 + R];
      const unsigned short* src = ebf + (size_t)tk * 256 + ((j ^ (R & 7)) << 3);
      gload_lds16(src, (void*)(xl + R0 * 256));
    }
  }
  __syncthreads();                          // barrier 1: x staged
  // Phase 1: [W|S] = X @ [c|m]^T; A from LDS (swizzled), B from global
  {
    const unsigned short* arow = xl + (16 * wv + r) * 256;
    const int sw = r & 7;
    const unsigned short* brow = (r < 8) ? (cbf + (size_t)b * 2048 + r * 256)
                                         : (mbf + (size_t)(r - 8) * 256);
    f32x4 acc = {0.f, 0.f, 0.f, 0.f};
#pragma unroll
    for (int kk = 0; kk < 8; ++kk) {
      const bf16x8 a  = *(const bf16x8*)(arow + (((kk * 4 + g) ^ sw) << 3));
      const bf16x8 bb = *(const bf16x8*)(brow + kk * 32 + g * 8);
      acc = __builtin_amdgcn_mfma_f32_16x16x32_bf16(a, bb, acc, 0, 0, 0);
    }
#pragma unroll
    for (int i = 0; i < 4; ++i)
      wslds[(16 * wv + g * 4 + i) * 17 + r] = acc[i];
  }
  __syncthreads();                          // barrier 2: logits complete
  // Phase 2: per-head softmax over seq
  {
#pragma unroll
    for (int hh = 0; hh < 2; ++hh) {
      const int h = 2 * wv + hh;
      const float v = wslds[l * 17 + h];
      float mx = v;
#pragma unroll
      for (int sft = 32; sft; sft >>= 1) mx = fmaxf(mx, __shfl_xor(mx, sft));
      const float e = expf(v - mx);
      float sm = e;
#pragma unroll
      for (int sft = 32; sft; sft >>= 1) sm += __shfl_xor(sm, sft);
      wslds[l * 17 + h] = e / sm;
    }
  }
  __syncthreads();                          // barrier 3: p complete
  // Phase 3: scores softmax -> coef -> cfT (bf16)
  {
    float p[8], sv[8];
#pragma unroll
    for (int h = 0; h < 8; ++h) { p[h] = wslds[l*17 + h]; sv[h] = wslds[l*17 + 8 + h]; }
    float sc = dense_b[0];
#pragma unroll
    for (int h = 0; h < 8; ++h) sc += p[h] * sv[h];
    float mx = sc;
#pragma unroll
    for (int sft = 32; sft; sft >>= 1) mx = fmaxf(mx, __shfl_xor(mx, sft));
    const float e = expf(sc - mx);
    float sm = e;
#pragma unroll
    for (int sft = 32; sft; sft >>= 1) sm += __shfl_xor(sm, sft);
    const float attn = e / sm;
    float cc0, cc1;
    if      (wv == 0) { cc0 = attn * p[0]; cc1 = attn * p[1]; }
    else if (wv == 1) { cc0 = attn * p[2]; cc1 = attn * p[3]; }
    else if (wv == 2) { cc0 = attn * p[4]; cc1 = attn * p[5]; }
    else              { cc0 = attn * p[6]; cc1 = attn * p[7]; }
    cfT[(2 * wv) * 80 + l]     = bf1(cc0);
    cfT[(2 * wv + 1) * 80 + l] = bf1(cc1);
  }
  __syncthreads();                          // barrier 4: cfT ready
  // Phase 4: Y = coefT @ X via MFMA; nt-skew per lane (B-cols lane-independent)
  {
    const bf16x8 a0 = *(const bf16x8*)(cfT + r * 80 + g * 8);        // k 0..31
    const bf16x8 a1 = *(const bf16x8*)(cfT + r * 80 + 32 + g * 8);   // k 32..63
    const short* xs = (const short*)xl;
#pragma unroll
    for (int ntt = 0; ntt < 4; ++ntt) {
      const int nt = (ntt + r) & 3;          // lane-skewed tile order
      const int d = wv * 64 + nt * 16 + r;
      short bv0[8], bv1[8];
#pragma unroll
      for (int j = 0; j < 8; ++j) {
        const int off = ((((d >> 3) ^ j) << 3) | (d & 7));
        bv0[j] = xs[(g * 8 + j) * 256 + off];
        bv1[j] = xs[(32 + g * 8 + j) * 256 + off];
      }
      f32x4 acc = {0.f, 0.f, 0.f, 0.f};
      acc = __builtin_amdgcn_mfma_f32_16x16x32_bf16(a0, *(const bf16x8*)bv0, acc, 0, 0, 0);
      acc = __builtin_amdgcn_mfma_f32_16x16x32_bf16(a1, *(const bf16x8*)bv1, acc, 0, 0, 0);
      if (g < 2) {
#pragma unroll
        for (int i = 0; i < 4; ++i) {
          const int h = g * 4 + i;
          cbf[(size_t)b * 2048 + h * 256 + d] = bf1(acc[i]);
        }
      }
    }
  }
}

// ---- K4: out[8192,256] = cbf[8192,2048] @ P  (MFMA; 32-row tiles, 1024 blocks)
__global__ __launch_bounds__(256) void pgemm(const unsigned short* __restrict__ cbf,
                                             const unsigned short* __restrict__ ptb,
                                             float* __restrict__ out) {
  __shared__ unsigned short As[32 * 264];   // 16,896 B
  const int t = threadIdx.x;
  const int m0 = blockIdx.x * 32, n0 = blockIdx.y * 64;
  const int wv = t >> 6, l = t & 63;
  const int g = l >> 4, r = l & 15;
  const int msub = wv & 1, nhalf = wv >> 1;
  f32x4 acc[2] = {};
  for (int kc = 0; kc < 8; ++kc) {
    __syncthreads();
#pragma unroll
    for (int it = 0; it < 4; ++it) {
      const int idx = it * 256 + t;
      const int row = idx >> 5, c = idx & 31;
      const uint4 v = *(const uint4*)(cbf + (size_t)(m0 + row) * 2048 + kc * 256 + c * 8);
      *(uint4*)(As + row * 264 + c * 8) = v;
    }
    __syncthreads();
#pragma unroll
    for (int kk = 0; kk < 8; ++kk) {
      const bf16x8 a = *(const bf16x8*)(As + (16 * msub + r) * 264 + kk * 32 + g * 8);
#pragma unroll
      for (int nt = 0; nt < 2; ++nt) {
        const int n = n0 + (nhalf * 2 + nt) * 16 + r;
        const bf16x8 bb = *(const bf16x8*)(ptb + (size_t)n * 2048 + kc * 256 + kk * 32 + g * 8);
        acc[nt] = __builtin_amdgcn_mfma_f32_16x16x32_bf16(a, bb, acc[nt], 0, 0, 0);
      }
    }
  }
#pragma unroll
  for (int nt = 0; nt < 2; ++nt) {
    const int n = n0 + (nhalf * 2 + nt) * 16 + r;
#pragma unroll
    for (int i = 0; i < 4; ++i)
      out[(size_t)(m0 + 16 * msub + g * 4 + i) * 256 + n] = acc[nt][i];
  }
}

extern "C" void kernel_launch(void* const* d_in, const int* in_sizes, int n_in,
                              void* d_out, int out_size, void* d_ws, size_t ws_size,
                              hipStream_t stream) {
  const int*   tokens = (const int*)d_in[0];
  const float* emb    = (const float*)d_in[1];
  const float* WQ     = (const float*)d_in[2];
  const float* WK     = (const float*)d_in[3];
  const float* WV     = (const float*)d_in[4];
  const float* WO     = (const float*)d_in[5];
  const float* dw     = (const float*)d_in[6];
  const float* db     = (const float*)d_in[7];
  float* out = (float*)d_out;

  // ushort-unit layout
  unsigned short* base = (unsigned short*)d_ws;
  unsigned short* mbf  = base;                           // 2048
  unsigned short* xbf  = base + 2048;                    // 8192*256   (4 MB)
  unsigned short* tkn  = xbf + (size_t)8192 * 256;       // 2048*256   (1 MB)
  unsigned short* cbf  = tkn + (size_t)2048 * 256;       // 8192*2048  (32 MB)
  unsigned short* ebf  = cbf + (size_t)8192 * 2048;      // 50000*256  (25.6 MB)
  unsigned short* ptb  = ebf + (size_t)50000 * 256;      // 256*2048   (1 MB)

  const size_t need_bytes = (size_t)(2048 + 8192*256 + 2048*256 + 8192*2048
                                     + 50000*256 + 256*2048) * 2;
  if (ws_size < need_bytes) return;  // deterministic no-op guard

  prep_all<<<dim3(321), dim3(256), 0, stream>>>(WQ, WK, WV, WO, dw, mbf, tkn, ptb);
  // emb f32 -> ebf bf16 (50000*256)
  ebf_kernel<<<dim3(2048), dim3(256), 0, stream>>>((const float4*)emb, (uint2*)ebf,
                                                   50000 * 64);
  xbar_kernel<<<dim3(8192), dim3(256), 0, stream>>>(tokens, ebf, xbf);
  // c[b][n] for all b,n in one MFMA GEMM
  cgemm<<<dim3(128, 32), dim3(256), 0, stream>>>(xbf, tkn, cbf);
  // main per-sample: logits, softmaxes, y via MFMA (overwrites c, bf16)
  main_kernel<<<dim3(8192), dim3(256), 0, stream>>>(tokens, ebf, mbf, db, cbf);
  // out = Y @ P in one MFMA GEMM (1024 blocks, 32x64 tiles)
  pgemm<<<dim3(256, 4), dim3(256), 0, stream>>>(cbf, ptb, out);
}